// Round 3
// baseline (517.241 us; speedup 1.0000x reference)
//
#include <hip/hip_runtime.h>
#include <stdint.h>

// ---------------------------------------------------------------------------
// Qwen2 MoE sparse block, MI355X/gfx950.  FP32 inputs/outputs (per reference
// setup_inputs: jnp.float32).  Internally bf16 MFMA: weight transposes fuse
// fp32->bf16; X converted in-register during A-staging.
// T=2048, D=2048, E=8, F=1408, top-2.  Sparse dispatch (~71 GFLOP vs 283).
// ---------------------------------------------------------------------------

#define TT 2048
#define DD 2048
#define FF 1408
#define NE 8
#define HROWS 5120          // >= sum of per-expert counts padded to 128 (<=5112)
#define TRASH (2*TT)        // Y trash row for pad entries

typedef float f32x4 __attribute__((ext_vector_type(4)));
typedef short bf16x8 __attribute__((ext_vector_type(8)));

__device__ __forceinline__ unsigned short f2bf(float f) {
    unsigned int x = __float_as_uint(f);
    return (unsigned short)((x + 0x7fffu + ((x >> 16) & 1u)) >> 16);
}
__device__ __forceinline__ float bf2f(unsigned short u) {
    union { unsigned int i; float f; } v; v.i = ((unsigned int)u) << 16; return v.f;
}
// 8 fp32 -> 8 bf16 packed in uint4
__device__ __forceinline__ uint4 cvt8(float4 a, float4 b) {
    uint4 o; unsigned short* po = (unsigned short*)&o;
    po[0] = f2bf(a.x); po[1] = f2bf(a.y); po[2] = f2bf(a.z); po[3] = f2bf(a.w);
    po[4] = f2bf(b.x); po[5] = f2bf(b.y); po[6] = f2bf(b.z); po[7] = f2bf(b.w);
    return o;
}

// ---------------------------------------------------------------------------
// Transpose + fp32->bf16 convert.  64x64 tile via LDS (+1 pad col).
// ---------------------------------------------------------------------------
__device__ __forceinline__ void transpose_tile(const float* __restrict__ src,
                                               unsigned short* __restrict__ dst,
                                               int R, int C, int r0, int c0) {
    __shared__ unsigned short tile[64][65];
    const int tid = threadIdx.x;
    const int lr = tid >> 3;          // 0..31
    const int lc = (tid & 7) * 8;     // 0..56 step 8
#pragma unroll
    for (int p = 0; p < 2; ++p) {
        int rr = lr + p * 32;
        const float* sp = &src[(size_t)(r0 + rr) * C + c0 + lc];
        float4 a = ((const float4*)sp)[0];
        float4 b = ((const float4*)sp)[1];
        uint4 v = cvt8(a, b);
        const unsigned short* pv = (const unsigned short*)&v;
#pragma unroll
        for (int i = 0; i < 8; ++i) tile[rr][lc + i] = pv[i];
    }
    __syncthreads();
#pragma unroll
    for (int p = 0; p < 2; ++p) {
        int cc = lr + p * 32;
        uint4 o; unsigned short* po = (unsigned short*)&o;
#pragma unroll
        for (int i = 0; i < 8; ++i) po[i] = tile[lc + i][cc];
        *(uint4*)&dst[(size_t)(c0 + cc) * R + r0 + lc] = o;
    }
}

// w_gate/w_up [E][D][F] fp32 -> [E][F][D] bf16.  grid (22, 32, 16)
__global__ void transpose_gu_kernel(const float* __restrict__ wg,
                                    const float* __restrict__ wu,
                                    unsigned short* __restrict__ WgT,
                                    unsigned short* __restrict__ WuT) {
    const int z = blockIdx.z;
    const float* src; unsigned short* dst;
    if (z < 8) { src = wg + (size_t)z * DD * FF;       dst = WgT + (size_t)z * FF * DD; }
    else       { src = wu + (size_t)(z - 8) * DD * FF; dst = WuT + (size_t)(z - 8) * FF * DD; }
    transpose_tile(src, dst, DD, FF, blockIdx.y * 64, blockIdx.x * 64);
}

// w_down [E][F][D] fp32 -> [E][D][F] bf16.  grid (32, 22, 8)
__global__ void transpose_d_kernel(const float* __restrict__ wd,
                                   unsigned short* __restrict__ WdT) {
    const int z = blockIdx.z;
    transpose_tile(wd + (size_t)z * FF * DD, WdT + (size_t)z * DD * FF,
                   FF, DD, blockIdx.y * 64, blockIdx.x * 64);
}

// ---------------------------------------------------------------------------
// Router: one wave per token, exact fp32.
// ---------------------------------------------------------------------------
__global__ void router_kernel(const float* __restrict__ x,
                              const float* __restrict__ gw,
                              int* __restrict__ cnt,
                              int* __restrict__ tok,
                              float* __restrict__ wtv,
                              int* __restrict__ dstv) {
    const int wv = threadIdx.x >> 6, lane = threadIdx.x & 63;
    const int t = blockIdx.x * 4 + wv;
    float acc[NE];
#pragma unroll
    for (int e = 0; e < NE; ++e) acc[e] = 0.f;
    const float* xr = x + (size_t)t * DD;
    for (int j = lane; j < DD; j += 64) {
        float xv = xr[j];
#pragma unroll
        for (int e = 0; e < NE; ++e) acc[e] += xv * gw[e * DD + j];
    }
#pragma unroll
    for (int e = 0; e < NE; ++e) {
        float v = acc[e];
        v += __shfl_xor(v, 32); v += __shfl_xor(v, 16); v += __shfl_xor(v, 8);
        v += __shfl_xor(v, 4);  v += __shfl_xor(v, 2);  v += __shfl_xor(v, 1);
        acc[e] = v;
    }
    if (lane == 0) {
        float mx = acc[0];
#pragma unroll
        for (int e = 1; e < NE; ++e) mx = fmaxf(mx, acc[e]);
        float p[NE], s = 0.f;
#pragma unroll
        for (int e = 0; e < NE; ++e) { p[e] = __expf(acc[e] - mx); s += p[e]; }
        int i0 = 0;
#pragma unroll
        for (int e = 1; e < NE; ++e) if (p[e] > p[i0]) i0 = e;
        int i1 = (i0 == 0) ? 1 : 0;
#pragma unroll
        for (int e = 0; e < NE; ++e) if (e != i0 && p[e] > p[i1]) i1 = e;
        float inv = 1.f / s;
        int p0 = atomicAdd(&cnt[i0], 1);
        tok[i0 * TT + p0] = t; wtv[i0 * TT + p0] = p[i0] * inv; dstv[i0 * TT + p0] = 2 * t;
        int p1 = atomicAdd(&cnt[i1], 1);
        tok[i1 * TT + p1] = t; wtv[i1 * TT + p1] = p[i1] * inv; dstv[i1 * TT + p1] = 2 * t + 1;
    }
}

// ---------------------------------------------------------------------------
// Finalize: pad lists to multiples of 128 (token 0, weight 0, dst=TRASH).
// ---------------------------------------------------------------------------
__global__ void finalize_kernel(const int* __restrict__ cnt,
                                int* __restrict__ base,
                                int* __restrict__ cntpad,
                                int* __restrict__ tok,
                                float* __restrict__ wtv,
                                int* __restrict__ dstv) {
    __shared__ int sc[NE], sp[NE];
    if (threadIdx.x == 0) {
        int b = 0;
        for (int e = 0; e < NE; ++e) {
            int c = cnt[e]; int pd = (c + 127) & ~127;
            base[e] = b; cntpad[e] = pd; sc[e] = c; sp[e] = pd; b += pd;
        }
    }
    __syncthreads();
    for (int e = 0; e < NE; ++e)
        for (int i = sc[e] + (int)threadIdx.x; i < sp[e]; i += 256) {
            tok[e * TT + i] = 0; wtv[e * TT + i] = 0.f; dstv[e * TT + i] = TRASH;
        }
}

// ---------------------------------------------------------------------------
// GEMM1 fused gate+up+silu*mul.  128x128 tile, K=32 steps.  A staged from
// fp32 X (gathered rows, converted in-register); B from bf16 WgT/WuT.
// ---------------------------------------------------------------------------
__launch_bounds__(256, 2)
__global__ void gemm1_kernel(const float* __restrict__ x,
                             const unsigned short* __restrict__ WgT,
                             const unsigned short* __restrict__ WuT,
                             const int* __restrict__ tok,
                             const int* __restrict__ base,
                             const int* __restrict__ cntpad,
                             unsigned short* __restrict__ H) {
    __shared__ unsigned short As[128 * 32];
    __shared__ unsigned short Bg[128 * 32];
    __shared__ unsigned short Bu[128 * 32];
    __shared__ int s_tok[128];

    const int e = blockIdx.z, rb = blockIdx.y, fb = blockIdx.x;
    const int cp = cntpad[e];
    if (rb * 128 >= cp) return;
    const int b0 = base[e];

    const int tid = threadIdx.x;
    if (tid < 128) s_tok[tid] = tok[e * TT + rb * 128 + tid];
    __syncthreads();

    const int w = tid >> 6, lane = tid & 63;
    const int r = lane & 15, q = lane >> 4;
    const int wm = w & 1, wn = w >> 1;

    const int srow = w * 32 + (lane >> 2);   // tile row this lane stages
    const int koff = (lane & 3) * 8;         // k-element offset within 32
    const float* ga0 = x + (size_t)s_tok[srow] * DD + koff;
    const float* ga1 = x + (size_t)s_tok[srow + 16] * DD + koff;
    const size_t wb = (size_t)e * FF * DD + (size_t)(fb * 128 + srow) * DD + koff;
    const unsigned short* gg0 = WgT + wb;
    const unsigned short* gg1 = WgT + wb + (size_t)16 * DD;
    const unsigned short* gu0 = WuT + wb;
    const unsigned short* gu1 = WuT + wb + (size_t)16 * DD;
    uint4* sa0 = (uint4*)&As[srow * 32 + koff];  uint4* sa1 = (uint4*)&As[(srow + 16) * 32 + koff];
    uint4* sg0 = (uint4*)&Bg[srow * 32 + koff];  uint4* sg1 = (uint4*)&Bg[(srow + 16) * 32 + koff];
    uint4* su0 = (uint4*)&Bu[srow * 32 + koff];  uint4* su1 = (uint4*)&Bu[(srow + 16) * 32 + koff];

    f32x4 accg[4][4] = {};
    f32x4 accu[4][4] = {};

    for (int kt = 0; kt < DD / 32; ++kt) {
        uint4 va0 = cvt8(((const float4*)ga0)[0], ((const float4*)ga0)[1]);
        uint4 va1 = cvt8(((const float4*)ga1)[0], ((const float4*)ga1)[1]);
        uint4 vg0 = *(const uint4*)gg0;  uint4 vg1 = *(const uint4*)gg1;
        uint4 vu0 = *(const uint4*)gu0;  uint4 vu1 = *(const uint4*)gu1;
        ga0 += 32; ga1 += 32; gg0 += 32; gg1 += 32; gu0 += 32; gu1 += 32;
        __syncthreads();                 // prev iter's fragment reads complete
        *sa0 = va0; *sa1 = va1; *sg0 = vg0; *sg1 = vg1; *su0 = vu0; *su1 = vu1;
        __syncthreads();                 // staging visible
        bf16x8 af[4], gf[4], uf[4];
#pragma unroll
        for (int m = 0; m < 4; ++m)
            af[m] = *(const bf16x8*)&As[(wm * 64 + m * 16 + r) * 32 + q * 8];
#pragma unroll
        for (int n = 0; n < 4; ++n) {
            gf[n] = *(const bf16x8*)&Bg[(wn * 64 + n * 16 + r) * 32 + q * 8];
            uf[n] = *(const bf16x8*)&Bu[(wn * 64 + n * 16 + r) * 32 + q * 8];
        }
#pragma unroll
        for (int m = 0; m < 4; ++m)
#pragma unroll
            for (int n = 0; n < 4; ++n) {
                accg[m][n] = __builtin_amdgcn_mfma_f32_16x16x32_bf16(af[m], gf[n], accg[m][n], 0, 0, 0);
                accu[m][n] = __builtin_amdgcn_mfma_f32_16x16x32_bf16(af[m], uf[n], accu[m][n], 0, 0, 0);
            }
    }

    const size_t hr0 = (size_t)(b0 + rb * 128 + wm * 64);
#pragma unroll
    for (int m = 0; m < 4; ++m)
#pragma unroll
        for (int n = 0; n < 4; ++n)
#pragma unroll
            for (int rr = 0; rr < 4; ++rr) {
                float g = accg[m][n][rr], u = accu[m][n][rr];
                float h = (g / (1.f + __expf(-g))) * u;      // silu(g)*u
                int row = m * 16 + q * 4 + rr;
                int col = fb * 128 + wn * 64 + n * 16 + r;
                H[(hr0 + row) * FF + col] = f2bf(h);
            }
}

// ---------------------------------------------------------------------------
// GEMM2: Y[dst_row, d] = weight * (H_row . WdT[d,:]).
// ---------------------------------------------------------------------------
__launch_bounds__(256, 2)
__global__ void gemm2_kernel(const unsigned short* __restrict__ H,
                             const unsigned short* __restrict__ WdT,
                             const float* __restrict__ wtv,
                             const int* __restrict__ dstv,
                             const int* __restrict__ base,
                             const int* __restrict__ cntpad,
                             unsigned short* __restrict__ Y) {
    __shared__ unsigned short As[128 * 32];
    __shared__ unsigned short Bs[128 * 32];
    __shared__ float s_w[128];
    __shared__ int s_d[128];

    const int e = blockIdx.z, rb = blockIdx.y, db = blockIdx.x;
    const int cp = cntpad[e];
    if (rb * 128 >= cp) return;
    const int b0 = base[e];

    const int tid = threadIdx.x;
    if (tid < 128) {
        int idx = e * TT + rb * 128 + tid;
        s_w[tid] = wtv[idx]; s_d[tid] = dstv[idx];
    }
    __syncthreads();

    const int w = tid >> 6, lane = tid & 63;
    const int r = lane & 15, q = lane >> 4;
    const int wm = w & 1, wn = w >> 1;

    const int srow = w * 32 + (lane >> 2);
    const int koff = (lane & 3) * 8;
    const unsigned short* ga0 = H + (size_t)(b0 + rb * 128 + srow) * FF + koff;
    const unsigned short* ga1 = ga0 + (size_t)16 * FF;
    const unsigned short* gb0 = WdT + (size_t)e * DD * FF + (size_t)(db * 128 + srow) * FF + koff;
    const unsigned short* gb1 = gb0 + (size_t)16 * FF;
    uint4* sa0 = (uint4*)&As[srow * 32 + koff];  uint4* sa1 = (uint4*)&As[(srow + 16) * 32 + koff];
    uint4* sb0 = (uint4*)&Bs[srow * 32 + koff];  uint4* sb1 = (uint4*)&Bs[(srow + 16) * 32 + koff];

    f32x4 acc[4][4] = {};

    for (int kt = 0; kt < FF / 32; ++kt) {
        uint4 va0 = *(const uint4*)ga0;  uint4 va1 = *(const uint4*)ga1;
        uint4 vb0 = *(const uint4*)gb0;  uint4 vb1 = *(const uint4*)gb1;
        ga0 += 32; ga1 += 32; gb0 += 32; gb1 += 32;
        __syncthreads();
        *sa0 = va0; *sa1 = va1; *sb0 = vb0; *sb1 = vb1;
        __syncthreads();
        bf16x8 af[4], bf[4];
#pragma unroll
        for (int m = 0; m < 4; ++m)
            af[m] = *(const bf16x8*)&As[(wm * 64 + m * 16 + r) * 32 + q * 8];
#pragma unroll
        for (int n = 0; n < 4; ++n)
            bf[n] = *(const bf16x8*)&Bs[(wn * 64 + n * 16 + r) * 32 + q * 8];
#pragma unroll
        for (int m = 0; m < 4; ++m)
#pragma unroll
            for (int n = 0; n < 4; ++n)
                acc[m][n] = __builtin_amdgcn_mfma_f32_16x16x32_bf16(af[m], bf[n], acc[m][n], 0, 0, 0);
    }

#pragma unroll
    for (int m = 0; m < 4; ++m)
#pragma unroll
        for (int n = 0; n < 4; ++n)
#pragma unroll
            for (int rr = 0; rr < 4; ++rr) {
                int row = wm * 64 + m * 16 + q * 4 + rr;
                int col = db * 128 + wn * 64 + n * 16 + r;
                float v = s_w[row] * acc[m][n][rr];
                Y[(size_t)s_d[row] * DD + col] = f2bf(v);
            }
}

// ---------------------------------------------------------------------------
// Combine: out[t,d] = Y[2t,d] + Y[2t+1,d]  -> fp32 out.
// ---------------------------------------------------------------------------
__global__ void combine_kernel(const unsigned short* __restrict__ Y,
                               float* __restrict__ out) {
    const int t = blockIdx.x;
    const int d = threadIdx.x * 8;
    uint4 a = *(const uint4*)(Y + (size_t)(2 * t) * DD + d);
    uint4 b = *(const uint4*)(Y + (size_t)(2 * t + 1) * DD + d);
    const unsigned short* pa = (const unsigned short*)&a;
    const unsigned short* pb = (const unsigned short*)&b;
    float4 o0, o1;
    o0.x = bf2f(pa[0]) + bf2f(pb[0]);  o0.y = bf2f(pa[1]) + bf2f(pb[1]);
    o0.z = bf2f(pa[2]) + bf2f(pb[2]);  o0.w = bf2f(pa[3]) + bf2f(pb[3]);
    o1.x = bf2f(pa[4]) + bf2f(pb[4]);  o1.y = bf2f(pa[5]) + bf2f(pb[5]);
    o1.z = bf2f(pa[6]) + bf2f(pb[6]);  o1.w = bf2f(pa[7]) + bf2f(pb[7]);
    float* op = out + (size_t)t * DD + d;
    ((float4*)op)[0] = o0;
    ((float4*)op)[1] = o1;
}

// ---------------------------------------------------------------------------
extern "C" void kernel_launch(void* const* d_in, const int* in_sizes, int n_in,
                              void* d_out, int out_size, void* d_ws, size_t ws_size,
                              hipStream_t stream) {
    const float* x      = (const float*)d_in[0];
    const float* gw     = (const float*)d_in[1];
    const float* w_gate = (const float*)d_in[2];
    const float* w_up   = (const float*)d_in[3];
    const float* w_down = (const float*)d_in[4];
    float* out = (float*)d_out;

    uint8_t* ws = (uint8_t*)d_ws;
    size_t off = 0;
    auto alloc = [&](size_t bytes) -> void* {
        void* p = ws + off;
        off = (off + bytes + 255) & ~(size_t)255;
        return p;
    };
    int*   cnt    = (int*)  alloc(NE * 4);
    int*   basep  = (int*)  alloc(NE * 4);
    int*   cntpad = (int*)  alloc(NE * 4);
    int*   tok    = (int*)  alloc((size_t)NE * TT * 4);
    float* wtv    = (float*)alloc((size_t)NE * TT * 4);
    int*   dstv   = (int*)  alloc((size_t)NE * TT * 4);
    unsigned short* Hb  = (unsigned short*)alloc((size_t)HROWS * FF * 2);
    unsigned short* Yb  = (unsigned short*)alloc((size_t)(2 * TT + 8) * DD * 2);
    // Reused region: WgT+WuT (bf16) for gemm1, then WdT aliases WgT for gemm2.
    unsigned short* WT  = (unsigned short*)alloc((size_t)2 * NE * FF * DD * 2);
    unsigned short* WgT = WT;
    unsigned short* WuT = WT + (size_t)NE * FF * DD;
    unsigned short* WdT = WT;
    (void)ws_size; (void)in_sizes; (void)n_in; (void)out_size;

    hipMemsetAsync(cnt, 0, NE * 4, stream);
    transpose_gu_kernel<<<dim3(22, 32, 16), 256, 0, stream>>>(w_gate, w_up, WgT, WuT);
    router_kernel<<<dim3(TT / 4), 256, 0, stream>>>(x, gw, cnt, tok, wtv, dstv);
    finalize_kernel<<<1, 256, 0, stream>>>(cnt, basep, cntpad, tok, wtv, dstv);
    gemm1_kernel<<<dim3(FF / 128, TT / 128, NE), 256, 0, stream>>>(x, WgT, WuT, tok, basep, cntpad, Hb);
    transpose_d_kernel<<<dim3(32, 22, 8), 256, 0, stream>>>(w_down, WdT);
    gemm2_kernel<<<dim3(DD / 128, TT / 128, NE), 256, 0, stream>>>(Hb, WdT, wtv, dstv, basep, cntpad, Yb);
    combine_kernel<<<dim3(TT), 256, 0, stream>>>(Yb, out);
}